// Round 1
// baseline (208.798 us; speedup 1.0000x reference)
//
#include <hip/hip_runtime.h>

// SparseGlobalBroadcast: out[n][c] = in_feat[n][c] + glob_feat[batch_idx[n]][c]
// N = 1e6, C = 128, B = 8, fp32. Pure memory-bound streaming op.
// Strategy: float4 vectorized grid-stride loop; glob_feat (4 KB) staged in LDS.

#define SGB_C   128
#define SGB_C4  (SGB_C / 4)   // 32 float4 per row -> row = idx >> 5

__global__ __launch_bounds__(256) void SparseGlobalBroadcast_27762668601803_kernel(
    const float4* __restrict__ in4,
    const float4* __restrict__ glob4,   // B * C4 float4s (B=8 -> 256 float4s)
    const int*    __restrict__ bidx,
    float4*       __restrict__ out4,
    int n4,                             // N * C/4 total float4 elements
    int b_times_c4)                     // B * C4 (number of glob float4s)
{
    __shared__ float4 g_lds[8 * SGB_C4];   // 4 KB (B=8)

    const int t = threadIdx.x;
    // Stage glob_feat into LDS: B*C4 = 256 float4s, one per thread.
    if (t < b_times_c4) g_lds[t] = glob4[t];
    __syncthreads();

    const int stride = gridDim.x * blockDim.x;
    for (int i = blockIdx.x * blockDim.x + t; i < n4; i += stride) {
        const int row = i >> 5;        // which sparse point (C4 == 32)
        const int col = i & (SGB_C4 - 1);
        const int b   = bidx[row];     // 32 consecutive lanes share this -> cached broadcast
        float4 a = in4[i];
        const float4 g = g_lds[b * SGB_C4 + col];
        a.x += g.x; a.y += g.y; a.z += g.z; a.w += g.w;
        out4[i] = a;
    }
}

extern "C" void kernel_launch(void* const* d_in, const int* in_sizes, int n_in,
                              void* d_out, int out_size, void* d_ws, size_t ws_size,
                              hipStream_t stream) {
    const float4* in4   = (const float4*)d_in[0];   // in_feat  [N, C] fp32
    const float4* glob4 = (const float4*)d_in[1];   // glob_feat [B, C] fp32
    const int*    bidx  = (const int*)d_in[2];      // batch_idx [N] int32
    float4*       out4  = (float4*)d_out;

    const int N  = in_sizes[2];                 // 1,000,000
    const int n4 = N * SGB_C4;                  // 32,000,000 float4 elements
    const int b_times_c4 = in_sizes[1] / 4;     // B * C4 = 256

    const int block = 256;
    int grid = (n4 + block - 1) / block;
    if (grid > 2048) grid = 2048;               // grid-stride the rest

    SparseGlobalBroadcast_27762668601803_kernel<<<grid, block, 0, stream>>>(
        in4, glob4, bidx, out4, n4, b_times_c4);
}